// Round 1
// baseline (191.716 us; speedup 1.0000x reference)
//
#include <hip/hip_runtime.h>
#include <math.h>

#define B_ 2
#define C_ 128
#define H_ 64
#define W_ 64
#define F_ 16
#define U_ 9
#define MD_ 4
#define UV_ 81
#define HW_ (H_*W_)
#define BF_ (B_*F_)

// cvol layout in workspace: cvol[uv][bf][pix], bf = b*F_+f
// out0 layout: out0[bf][ch][pix], ch in {flowx, flowy, local_ent, global_ent}

__global__ __launch_bounds__(256)
void cvol_kernel(const float* __restrict__ ref,
                 const float* __restrict__ tar,
                 const float* __restrict__ pw,
                 float* __restrict__ cvol) {
    __shared__ float wlds[F_ * C_];
    int t = threadIdx.x;
    for (int i = t; i < F_ * C_; i += 256) wlds[i] = pw[i];
    __syncthreads();

    int pix = blockIdx.x * 256 + t;        // 0..4095
    int uv  = blockIdx.y;                  // 0..80 ; u = x-shift idx, v = y-shift idx
    int b   = blockIdx.z;
    int y = pix >> 6, x = pix & 63;
    int du = uv / U_ - MD_;                // x displacement
    int dv = uv % U_ - MD_;                // y displacement
    int ys = y + dv, xs = x + du;
    bool valid = ((unsigned)xs < (unsigned)W_) && ((unsigned)ys < (unsigned)H_);

    const float* rp = ref + (size_t)b * C_ * HW_ + pix;
    const float* tp = tar + (size_t)b * C_ * HW_ + (ys * W_ + xs);

    float acc[F_];
#pragma unroll
    for (int f = 0; f < F_; ++f) acc[f] = 0.f;

    for (int c = 0; c < C_; ++c) {
        float rv = rp[c * HW_];
        float tv = valid ? tp[c * HW_] : 0.f;   // zero-padded shift
        float p = rv * tv;
        p = p > 0.f ? p : 0.1f * p;             // leaky_relu(.,0.1); lrelu(0)=0
#pragma unroll
        for (int f = 0; f < F_; ++f) acc[f] = fmaf(wlds[f * C_ + c], p, acc[f]);
    }

    float* op = cvol + ((size_t)uv * BF_ + (size_t)b * F_) * HW_ + pix;
#pragma unroll
    for (int f = 0; f < F_; ++f) op[f * HW_] = acc[f];
}

__global__ __launch_bounds__(256)
void flowreg_kernel(const float* __restrict__ cvol,
                    float* __restrict__ out0) {
    int tid = blockIdx.x * 256 + threadIdx.x;   // over BF_*HW_
    int pix = tid & (HW_ - 1);
    int bf  = tid >> 12;                        // HW_ = 4096
    const float* cp = cvol + (size_t)bf * HW_ + pix;
    const size_t stride = (size_t)BF_ * HW_;

    // pass 1: argmax (first occurrence, matching jnp.argmax)
    float m = -1e30f; int best = 0;
    for (int uv = 0; uv < UV_; ++uv) {
        float v = cp[(size_t)uv * stride];
        if (v > m) { m = v; best = uv; }
    }
    int ub = best / U_;   // x-shift index of argmax
    int vb = best % U_;   // y-shift index

    float S = 0.f, A = 0.f, Sx = 0.f, Sy = 0.f, gS = 0.f, gA = 0.f;
    for (int uv = 0; uv < UV_; ++uv) {
        float xv = cp[(size_t)uv * stride];
        float d = xv - m;
        float z = __expf(d);
        gS += z; gA += z * d;
        int u = uv / U_, v = uv - u * U_;
        int duc = u - ub, dvc = v - vb;
        bool msk = (duc <= 3) && (duc >= -3) && (dvc <= 3) && (dvc >= -3);
        if (msk) {
            S += z; A += z * d;
            Sx += z * (float)(u - MD_);
            Sy += z * (float)(v - MD_);
        }
    }
    float invS = 1.f / S;
    float outx = Sx * invS;
    float outy = Sy * invS;
    // sum p*log p = A/S - log S  (p = z/S, log p = d - log S)
    float lent = (logf(S)  - A * invS) * (1.0f / logf(49.0f));
    float gent = (logf(gS) - gA / gS)  * (1.0f / logf(81.0f));

    float* op = out0 + (size_t)bf * 4 * HW_ + pix;
    op[0 * HW_] = outx;
    op[1 * HW_] = outy;
    op[2 * HW_] = lent;
    op[3 * HW_] = gent;
}

__global__ __launch_bounds__(256)
void warp_kernel(const float* __restrict__ tar,
                 const float* __restrict__ out0,
                 float* __restrict__ warped) {
    int tid = blockIdx.x * 256 + threadIdx.x;   // over B_*C_*HW_
    int pix = tid & (HW_ - 1);
    int bc  = tid >> 12;
    int b   = bc >> 7;                          // C_ = 128
    int x = pix & 63, y = pix >> 6;

    // flow = hypothesis f=0 of out0 for this b
    const float* fbase = out0 + (size_t)(b * F_) * 4 * HW_;
    float fx = fbase[pix];
    float fy = fbase[HW_ + pix];
    float px = (float)x + fx;
    float py = (float)y + fy;

    bool inb = (fabsf(2.0f * px / (float)(W_ - 1) - 1.0f) < 1.0f) &&
               (fabsf(2.0f * py / (float)(H_ - 1) - 1.0f) < 1.0f);

    float x0 = floorf(px), y0 = floorf(py);
    float wx = px - x0,    wy = py - y0;
    int x0i = (int)x0, y0i = (int)y0;

    const float* img = tar + (size_t)bc * HW_;

    auto tap = [&](int yi, int xi, float wgt) -> float {
        bool v = ((unsigned)xi < (unsigned)W_) && ((unsigned)yi < (unsigned)H_);
        int xc = xi < 0 ? 0 : (xi > W_ - 1 ? W_ - 1 : xi);
        int yc = yi < 0 ? 0 : (yi > H_ - 1 ? H_ - 1 : yi);
        float val = img[yc * W_ + xc];
        return val * (v ? wgt : 0.f);
    };

    float acc = tap(y0i,     x0i,     (1.f - wx) * (1.f - wy))
              + tap(y0i,     x0i + 1, wx * (1.f - wy))
              + tap(y0i + 1, x0i,     (1.f - wx) * wy)
              + tap(y0i + 1, x0i + 1, wx * wy);

    warped[tid] = inb ? acc : 0.f;
}

extern "C" void kernel_launch(void* const* d_in, const int* in_sizes, int n_in,
                              void* d_out, int out_size, void* d_ws, size_t ws_size,
                              hipStream_t stream) {
    const float* ref = (const float*)d_in[0];
    const float* tar = (const float*)d_in[1];
    const float* pw  = (const float*)d_in[2];
    float* out0 = (float*)d_out;                       // (B*F, 4, H, W) = 524288 floats
    float* out1 = out0 + (size_t)BF_ * 4 * HW_;        // (B, C, H, W)  = 2097152 floats
    float* cvol = (float*)d_ws;                        // 81*32*4096 floats = 42.5 MB

    dim3 g1(HW_ / 256, UV_, B_);
    cvol_kernel<<<g1, 256, 0, stream>>>(ref, tar, pw, cvol);
    flowreg_kernel<<<(BF_ * HW_) / 256, 256, 0, stream>>>(cvol, out0);
    warp_kernel<<<(B_ * C_ * HW_) / 256, 256, 0, stream>>>(tar, out0, out1);
}

// Round 2
// 151.573 us; speedup vs baseline: 1.2648x; 1.2648x over previous
//
#include <hip/hip_runtime.h>
#include <math.h>

#define B_ 2
#define C_ 128
#define H_ 64
#define W_ 64
#define F_ 16
#define U_ 9
#define MD_ 4
#define UV_ 81
#define HW_ (H_*W_)
#define BF_ (B_*F_)

// cvol layout in workspace: cvol[uv][bf][pix], bf = b*F_+f
// out0 layout: out0[bf][ch][pix], ch in {flowx, flowy, local_ent, global_ent}

__global__ __launch_bounds__(256)
void cvol_kernel(const float* __restrict__ ref,
                 const float* __restrict__ tar,
                 const float* __restrict__ pw,
                 float* __restrict__ cvol) {
    int t = threadIdx.x;
    int pix = blockIdx.x * 256 + t;        // 0..4095
    int uv  = blockIdx.y;                  // 0..80 ; u = x-shift idx, v = y-shift idx
    int b   = blockIdx.z;
    int y = pix >> 6, x = pix & 63;
    int du = uv / U_ - MD_;                // x displacement
    int dv = uv % U_ - MD_;                // y displacement
    int ys = y + dv, xs = x + du;
    bool valid = ((unsigned)xs < (unsigned)W_) && ((unsigned)ys < (unsigned)H_);

    const float* rp = ref + (size_t)b * C_ * HW_ + pix;
    const float* tp = tar + (size_t)b * C_ * HW_ + (ys * W_ + xs);

    float acc[F_];
#pragma unroll
    for (int f = 0; f < F_; ++f) acc[f] = 0.f;

    // weights read with wave-uniform indices -> scalar K$ loads (no LDS, no VALU)
    for (int c = 0; c < C_; c += 4) {
        float rv0 = rp[(c + 0) * HW_];
        float rv1 = rp[(c + 1) * HW_];
        float rv2 = rp[(c + 2) * HW_];
        float rv3 = rp[(c + 3) * HW_];
        float tv0 = valid ? tp[(c + 0) * HW_] : 0.f;
        float tv1 = valid ? tp[(c + 1) * HW_] : 0.f;
        float tv2 = valid ? tp[(c + 2) * HW_] : 0.f;
        float tv3 = valid ? tp[(c + 3) * HW_] : 0.f;
        float p0 = rv0 * tv0; p0 = p0 > 0.f ? p0 : 0.1f * p0;
        float p1 = rv1 * tv1; p1 = p1 > 0.f ? p1 : 0.1f * p1;
        float p2 = rv2 * tv2; p2 = p2 > 0.f ? p2 : 0.1f * p2;
        float p3 = rv3 * tv3; p3 = p3 > 0.f ? p3 : 0.1f * p3;
#pragma unroll
        for (int f = 0; f < F_; ++f) {
            const float* wr = pw + f * C_ + c;   // uniform address -> s_load
            float a = acc[f];
            a = fmaf(wr[0], p0, a);
            a = fmaf(wr[1], p1, a);
            a = fmaf(wr[2], p2, a);
            a = fmaf(wr[3], p3, a);
            acc[f] = a;
        }
    }

    float* op = cvol + ((size_t)uv * BF_ + (size_t)b * F_) * HW_ + pix;
#pragma unroll
    for (int f = 0; f < F_; ++f) op[f * HW_] = acc[f];
}

__global__ __launch_bounds__(256)
void flowreg_kernel(const float* __restrict__ cvol,
                    float* __restrict__ out0) {
    int tid = blockIdx.x * 256 + threadIdx.x;   // over BF_*HW_
    int pix = tid & (HW_ - 1);
    int bf  = tid >> 12;                        // HW_ = 4096
    const float* cp = cvol + (size_t)bf * HW_ + pix;
    const size_t stride = (size_t)BF_ * HW_;

    // single load round: cache all 81 uv values in registers
    float v[UV_];
#pragma unroll
    for (int uv = 0; uv < UV_; ++uv) v[uv] = cp[(size_t)uv * stride];

    // argmax (first occurrence, matching jnp.argmax)
    float m = v[0]; int best = 0;
#pragma unroll
    for (int uv = 1; uv < UV_; ++uv) {
        if (v[uv] > m) { m = v[uv]; best = uv; }
    }
    int ub = best / U_;   // x-shift index of argmax
    int vb = best - ub * U_;

    float S = 0.f, A = 0.f, Sx = 0.f, Sy = 0.f, gS = 0.f, gA = 0.f;
#pragma unroll
    for (int uv = 0; uv < UV_; ++uv) {
        float d = v[uv] - m;
        float z = __expf(d);
        gS += z; gA = fmaf(z, d, gA);
        int u = uv / U_, vy = uv - u * U_;      // compile-time constants
        int duc = u - ub, dvc = vy - vb;
        bool msk = (duc <= 3) && (duc >= -3) && (dvc <= 3) && (dvc >= -3);
        float zm = msk ? z : 0.f;
        float dm = msk ? d : 0.f;
        S += zm;
        A = fmaf(zm, dm, A);
        Sx = fmaf(zm, (float)(u - MD_), Sx);
        Sy = fmaf(zm, (float)(vy - MD_), Sy);
    }
    float invS = 1.f / S;
    float outx = Sx * invS;
    float outy = Sy * invS;
    // sum p*log p = A/S - log S  (p = z/S, log p = d - log S)
    float lent = (logf(S)  - A * invS) * (1.0f / logf(49.0f));
    float gent = (logf(gS) - gA / gS)  * (1.0f / logf(81.0f));

    float* op = out0 + (size_t)bf * 4 * HW_ + pix;
    op[0 * HW_] = outx;
    op[1 * HW_] = outy;
    op[2 * HW_] = lent;
    op[3 * HW_] = gent;
}

__global__ __launch_bounds__(256)
void warp_kernel(const float* __restrict__ tar,
                 const float* __restrict__ out0,
                 float* __restrict__ warped) {
    int tid = blockIdx.x * 256 + threadIdx.x;   // over B_*C_*HW_
    int pix = tid & (HW_ - 1);
    int bc  = tid >> 12;
    int b   = bc >> 7;                          // C_ = 128
    int x = pix & 63, y = pix >> 6;

    // flow = hypothesis f=0 of out0 for this b
    const float* fbase = out0 + (size_t)(b * F_) * 4 * HW_;
    float fx = fbase[pix];
    float fy = fbase[HW_ + pix];
    float px = (float)x + fx;
    float py = (float)y + fy;

    bool inb = (fabsf(2.0f * px / (float)(W_ - 1) - 1.0f) < 1.0f) &&
               (fabsf(2.0f * py / (float)(H_ - 1) - 1.0f) < 1.0f);

    float x0 = floorf(px), y0 = floorf(py);
    float wx = px - x0,    wy = py - y0;
    int x0i = (int)x0, y0i = (int)y0;

    const float* img = tar + (size_t)bc * HW_;

    auto tap = [&](int yi, int xi, float wgt) -> float {
        bool v = ((unsigned)xi < (unsigned)W_) && ((unsigned)yi < (unsigned)H_);
        int xc = xi < 0 ? 0 : (xi > W_ - 1 ? W_ - 1 : xi);
        int yc = yi < 0 ? 0 : (yi > H_ - 1 ? H_ - 1 : yi);
        float val = img[yc * W_ + xc];
        return val * (v ? wgt : 0.f);
    };

    float acc = tap(y0i,     x0i,     (1.f - wx) * (1.f - wy))
              + tap(y0i,     x0i + 1, wx * (1.f - wy))
              + tap(y0i + 1, x0i,     (1.f - wx) * wy)
              + tap(y0i + 1, x0i + 1, wx * wy);

    warped[tid] = inb ? acc : 0.f;
}

extern "C" void kernel_launch(void* const* d_in, const int* in_sizes, int n_in,
                              void* d_out, int out_size, void* d_ws, size_t ws_size,
                              hipStream_t stream) {
    const float* ref = (const float*)d_in[0];
    const float* tar = (const float*)d_in[1];
    const float* pw  = (const float*)d_in[2];
    float* out0 = (float*)d_out;                       // (B*F, 4, H, W) = 524288 floats
    float* out1 = out0 + (size_t)BF_ * 4 * HW_;        // (B, C, H, W)  = 2097152 floats
    float* cvol = (float*)d_ws;                        // 81*32*4096 floats = 42.5 MB

    dim3 g1(HW_ / 256, UV_, B_);
    cvol_kernel<<<g1, 256, 0, stream>>>(ref, tar, pw, cvol);
    flowreg_kernel<<<(BF_ * HW_) / 256, 256, 0, stream>>>(cvol, out0);
    warp_kernel<<<(B_ * C_ * HW_) / 256, 256, 0, stream>>>(tar, out0, out1);
}